// Round 2
// baseline (500.348 us; speedup 1.0000x reference)
//
#include <hip/hip_runtime.h>
#include <hip/hip_bf16.h>

typedef float  f32x4  __attribute__((ext_vector_type(4)));
typedef short  s16x8  __attribute__((ext_vector_type(8)));
typedef short  s16x4  __attribute__((ext_vector_type(4)));
typedef unsigned int u32x4 __attribute__((ext_vector_type(4)));

static __device__ __forceinline__ unsigned short f2bf(float f){
  union { float f; unsigned u; } v; v.f = f;
  unsigned r = v.u + 0x7fffu + ((v.u >> 16) & 1u);
  return (unsigned short)(r >> 16);
}

// ---------------------------------------------------------------------------
// kT: fmap [b][512][1024] f32  ->  fmapT [b][1024][512] bf16
// grid (16 ctiles, 4 itiles, 8 b), block 256
__global__ __launch_bounds__(256) void kT(const float* __restrict__ fmap,
                                          unsigned short* __restrict__ fmapT){
  int c0 = blockIdx.x * 32;
  int i0 = blockIdx.y * 256;
  int b  = blockIdx.z;
  int t  = threadIdx.x;
  const float* src = fmap + ((size_t)b*512 + c0)*1024 + i0 + t;
  unsigned pack[16];
  #pragma unroll
  for (int cc = 0; cc < 32; ++cc){
    unsigned short hv = f2bf(src[(size_t)cc*1024]);
    if ((cc & 1) == 0) pack[cc>>1] = hv;
    else               pack[cc>>1] |= ((unsigned)hv) << 16;
  }
  unsigned short* dst = fmapT + ((size_t)b*1024 + i0 + t)*512 + c0;
  #pragma unroll
  for (int q = 0; q < 4; ++q){
    u32x4 v; v[0]=pack[q*4+0]; v[1]=pack[q*4+1]; v[2]=pack[q*4+2]; v[3]=pack[q*4+3];
    *(u32x4*)(dst + q*8) = v;
  }
}

// ---------------------------------------------------------------------------
// kW: convert w_qkv [1536][512], rel_w [63][64], rel_h [63][64] f32 -> bf16
// chunks of 8 elems: W=98304, relw=504, relh=504 -> 99312 total, grid 388x256
__global__ __launch_bounds__(256) void kW(const float* __restrict__ W,
                                          const float* __restrict__ relw,
                                          const float* __restrict__ relh,
                                          unsigned short* __restrict__ Wb,
                                          unsigned short* __restrict__ relwb,
                                          unsigned short* __restrict__ relhb){
  int gid = blockIdx.x*256 + threadIdx.x;
  if (gid >= 99312) return;
  const float* s; unsigned short* d;
  if (gid < 98304){ s = W + (size_t)gid*8;            d = Wb    + (size_t)gid*8; }
  else if (gid < 98808){ int c = gid-98304; s = relw + (size_t)c*8; d = relwb + (size_t)c*8; }
  else {                 int c = gid-98808; s = relh + (size_t)c*8; d = relhb + (size_t)c*8; }
  unsigned pack[4];
  #pragma unroll
  for (int e = 0; e < 8; ++e){
    unsigned short hv = f2bf(s[e]);
    if ((e & 1) == 0) pack[e>>1] = hv;
    else              pack[e>>1] |= ((unsigned)hv) << 16;
  }
  u32x4 v; v[0]=pack[0]; v[1]=pack[1]; v[2]=pack[2]; v[3]=pack[3];
  *(u32x4*)d = v;
}

// ---------------------------------------------------------------------------
// kG: QKV projection GEMM (bf16 MFMA, fp32 acc).
// D[m][n] = sum_c A[m][c]*B[n][c], A,B row-major [*][512].
//  blocks 0..511  (Q/K): A=fmapT rows i, B=Wb rows o(0..1023), D[i][o]
//  blocks 512..767 (V) : A=Wb rows o(1024..1535), B=fmapT rows i, D[o][i]
// tile 128x128, 4 waves (2x2), K-step 32.
__global__ __launch_bounds__(256) void kG(const unsigned short* __restrict__ fmapT,
                                          const unsigned short* __restrict__ Wb,
                                          unsigned short* __restrict__ Qs,
                                          unsigned short* __restrict__ Kb,
                                          unsigned short* __restrict__ VT){
  __shared__ unsigned short Al[128*40];
  __shared__ unsigned short Bl[128*40];
  int bx = blockIdx.x;
  bool vpart = (bx >= 512);
  int b, iblk, oblk, ovb = 0;
  const unsigned short *Ag, *Bg;
  if (!vpart){
    b = bx >> 6; int rem = bx & 63; iblk = rem >> 3; oblk = rem & 7;
    Ag = fmapT + ((size_t)b*1024 + iblk*128)*512;
    Bg = Wb    + ((size_t)oblk*128)*512;
  } else {
    int r2 = bx - 512; b = r2 >> 5; int r3 = r2 & 31; ovb = r3 >> 3; iblk = r3 & 7;
    Ag = Wb    + ((size_t)(1024 + ovb*128))*512;
    Bg = fmapT + ((size_t)b*1024 + iblk*128)*512;
  }
  int tid  = threadIdx.x;
  int w    = tid >> 6, lane = tid & 63, li = lane & 15, g = lane >> 4;
  int wr   = w >> 1,  wc = w & 1;
  f32x4 acc[4][4] = {};
  for (int c0 = 0; c0 < 512; c0 += 32){
    __syncthreads();
    #pragma unroll
    for (int it = 0; it < 2; ++it){
      int idx = tid + it*256;
      int row = idx >> 2, cq = (idx & 3)*8;
      *(s16x8*)&Al[row*40 + cq] = *(const s16x8*)&Ag[(size_t)row*512 + c0 + cq];
      *(s16x8*)&Bl[row*40 + cq] = *(const s16x8*)&Bg[(size_t)row*512 + c0 + cq];
    }
    __syncthreads();
    s16x8 a[4], bb[4];
    #pragma unroll
    for (int f = 0; f < 4; ++f){
      a[f]  = *(const s16x8*)&Al[(wr*64 + f*16 + li)*40 + g*8];
      bb[f] = *(const s16x8*)&Bl[(wc*64 + f*16 + li)*40 + g*8];
    }
    #pragma unroll
    for (int fr = 0; fr < 4; ++fr)
      #pragma unroll
      for (int fc = 0; fc < 4; ++fc)
        acc[fr][fc] = __builtin_amdgcn_mfma_f32_16x16x32_bf16(a[fr], bb[fc], acc[fr][fc], 0,0,0);
  }
  if (!vpart){
    #pragma unroll
    for (int fr = 0; fr < 4; ++fr)
      #pragma unroll
      for (int fc = 0; fc < 4; ++fc)
        #pragma unroll
        for (int r = 0; r < 4; ++r){
          int i = iblk*128 + wr*64 + fr*16 + g*4 + r;     // D row
          int o = oblk*128 + wc*64 + fc*16 + li;          // D col
          float v = acc[fr][fc][r];
          int dd = o & 63;
          if (o < 512){
            int head = o >> 6;
            Qs[(((size_t)b*8 + head)*1024 + i)*64 + dd] = f2bf(v * 0.125f);
          } else {
            int head = (o - 512) >> 6;
            Kb[(((size_t)b*8 + head)*1024 + i)*64 + dd] = f2bf(v);
          }
        }
  } else {
    #pragma unroll
    for (int fr = 0; fr < 4; ++fr)
      #pragma unroll
      for (int fc = 0; fc < 4; ++fc)
        #pragma unroll
        for (int r = 0; r < 4; ++r){
          int o = 1024 + ovb*128 + wr*64 + fr*16 + g*4 + r;  // D row (V channel)
          int i = iblk*128 + wc*64 + fc*16 + li;             // D col
          int head = (o - 1024) >> 6, dd = o & 63;
          VT[(((size_t)b*8 + head)*64 + dd)*1024 + i] = f2bf(acc[fr][fc][r]);
        }
  }
}

// ---------------------------------------------------------------------------
// kR: expanded relative logits.
// type0: RWE[bh][i][jy] = dot(Qs[bh][i], relw[jy-(i&31)+31]);  wave fixes s=iy
// type1: RHE[bh][i][jx] = dot(Qs[bh][i], relh[jx-(i>>5)+31]);  wave fixes s=ix
// grid (64 bh, 8, 2 type), block 256 (4 waves, s = by*4+w)
__global__ __launch_bounds__(256) void kR(const unsigned short* __restrict__ Qs,
                                          const unsigned short* __restrict__ relwb,
                                          const unsigned short* __restrict__ relhb,
                                          float* __restrict__ RWE,
                                          float* __restrict__ RHE){
  int bh = blockIdx.x, type = blockIdx.z;
  int w = threadIdx.x >> 6, lane = threadIdx.x & 63, li = lane & 15, g = lane >> 4;
  int s = blockIdx.y*4 + w;
  const unsigned short* rel = type ? relhb : relwb;
  s16x8 a[2][2], bb[2][2];
  #pragma unroll
  for (int mt = 0; mt < 2; ++mt)
    #pragma unroll
    for (int kt = 0; kt < 2; ++kt){
      int m = mt*16 + li;                                  // row within 32
      int i = type ? (s*32 + m) : (m*32 + s);
      a[mt][kt] = *(const s16x8*)&Qs[((size_t)bh*1024 + i)*64 + kt*32 + g*8];
    }
  #pragma unroll
  for (int nt = 0; nt < 2; ++nt)
    #pragma unroll
    for (int kt = 0; kt < 2; ++kt){
      int mrel = (nt*16 + li) - s + 31;                    // in [0,62]
      bb[nt][kt] = *(const s16x8*)&rel[(size_t)mrel*64 + kt*32 + g*8];
    }
  f32x4 acc[2][2] = {};
  #pragma unroll
  for (int mt = 0; mt < 2; ++mt)
    #pragma unroll
    for (int nt = 0; nt < 2; ++nt){
      acc[mt][nt] = __builtin_amdgcn_mfma_f32_16x16x32_bf16(a[mt][0], bb[nt][0], acc[mt][nt], 0,0,0);
      acc[mt][nt] = __builtin_amdgcn_mfma_f32_16x16x32_bf16(a[mt][1], bb[nt][1], acc[mt][nt], 0,0,0);
    }
  float* dst = type ? RHE : RWE;
  #pragma unroll
  for (int mt = 0; mt < 2; ++mt)
    #pragma unroll
    for (int nt = 0; nt < 2; ++nt)
      #pragma unroll
      for (int r = 0; r < 4; ++r){
        int m = mt*16 + g*4 + r;
        int i = type ? (s*32 + m) : (m*32 + s);
        dst[((size_t)bh*1024 + i)*32 + nt*16 + li] = acc[mt][nt][r];
      }
}

// ---------------------------------------------------------------------------
// kA: fused attention. Computes S^T tiles via mfma(K,Q), adds pos, streams sim,
// online softmax (state per lane: i = i0 + (lane&15)), PV via 16x16x16 mfma.
// grid (16 iblk, 64 bh), block 256 (4 waves x 16 q-rows)
__global__ __launch_bounds__(256) void kA(const unsigned short* __restrict__ Qs,
                                          const unsigned short* __restrict__ Kb,
                                          const unsigned short* __restrict__ VT,
                                          const float* __restrict__ RWE,
                                          const float* __restrict__ RHE,
                                          float* __restrict__ out){
  int bh = blockIdx.y;
  int w = threadIdx.x >> 6, lane = threadIdx.x & 63, li = lane & 15, g = lane >> 4;
  int i = blockIdx.x*64 + w*16 + li;                       // this lane's q-row
  const unsigned short* qrow = Qs + ((size_t)bh*1024 + i)*64;
  s16x8 bq0 = *(const s16x8*)&qrow[g*8];
  s16x8 bq1 = *(const s16x8*)&qrow[32 + g*8];
  const float* rwe = RWE + ((size_t)bh*1024 + i)*32;
  f32x4 rlo = *(const f32x4*)&rwe[g*4];                    // jy = g*4+r      (tile parity 0)
  f32x4 rhi = *(const f32x4*)&rwe[16 + g*4];               // jy = 16+g*4+r   (tile parity 1)
  const float* rhe = RHE + ((size_t)bh*1024 + i)*32;
  const unsigned short* Kbase = Kb + (size_t)bh*1024*64;
  const unsigned short* Vbase = VT + (size_t)bh*64*1024;
  float* simbase = out + 4194304 + ((size_t)bh*1024 + i)*1024;
  float M = -1e30f, L = 0.f;
  f32x4 o0 = {}, o1 = {}, o2 = {}, o3 = {};
  for (int jc = 0; jc < 32; ++jc){
    float rh = rhe[jc];                                    // jx = jc for whole chunk
    #pragma unroll
    for (int t2 = 0; t2 < 2; ++t2){
      int j0 = jc*32 + t2*16;
      const unsigned short* krow = Kbase + (size_t)(j0 + li)*64;
      s16x8 ak0 = *(const s16x8*)&krow[g*8];
      s16x8 ak1 = *(const s16x8*)&krow[32 + g*8];
      f32x4 sAcc = {};
      sAcc = __builtin_amdgcn_mfma_f32_16x16x32_bf16(ak0, bq0, sAcc, 0,0,0);
      sAcc = __builtin_amdgcn_mfma_f32_16x16x32_bf16(ak1, bq1, sAcc, 0,0,0);
      f32x4 radd = t2 ? rhi : rlo;
      #pragma unroll
      for (int r = 0; r < 4; ++r) sAcc[r] += radd[r] + rh;
      *(f32x4*)&simbase[j0 + g*4] = sAcc;                  // pre-softmax sim, j-contig 16B
      // online softmax (reduce the 16 j's of this tile for column i)
      float tm = fmaxf(fmaxf(sAcc[0], sAcc[1]), fmaxf(sAcc[2], sAcc[3]));
      tm = fmaxf(tm, __shfl_xor(tm, 16));
      tm = fmaxf(tm, __shfl_xor(tm, 32));
      float nM = fmaxf(M, tm);
      float sc = __expf(M - nM);
      f32x4 p;
      #pragma unroll
      for (int r = 0; r < 4; ++r) p[r] = __expf(sAcc[r] - nM);
      float ts = p[0] + p[1] + p[2] + p[3];
      ts += __shfl_xor(ts, 16);
      ts += __shfl_xor(ts, 32);
      L = L*sc + ts;
      M = nM;
      o0 *= sc; o1 *= sc; o2 *= sc; o3 *= sc;
      s16x4 pb;
      #pragma unroll
      for (int r = 0; r < 4; ++r) pb[r] = (short)f2bf(p[r]);
      const unsigned short* vcol = Vbase + j0 + g*4;
      s16x4 av0 = *(const s16x4*)&vcol[(size_t)( 0 + li)*1024];
      s16x4 av1 = *(const s16x4*)&vcol[(size_t)(16 + li)*1024];
      s16x4 av2 = *(const s16x4*)&vcol[(size_t)(32 + li)*1024];
      s16x4 av3 = *(const s16x4*)&vcol[(size_t)(48 + li)*1024];
      o0 = __builtin_amdgcn_mfma_f32_16x16x16bf16_1k(av0, pb, o0, 0,0,0);
      o1 = __builtin_amdgcn_mfma_f32_16x16x16bf16_1k(av1, pb, o1, 0,0,0);
      o2 = __builtin_amdgcn_mfma_f32_16x16x16bf16_1k(av2, pb, o2, 0,0,0);
      o3 = __builtin_amdgcn_mfma_f32_16x16x16bf16_1k(av3, pb, o3, 0,0,0);
    }
  }
  float invL = 1.0f / L;
  f32x4 oo[4] = {o0, o1, o2, o3};
  #pragma unroll
  for (int dt = 0; dt < 4; ++dt)
    #pragma unroll
    for (int r = 0; r < 4; ++r)
      out[((size_t)bh*64 + dt*16 + g*4 + r)*1024 + i] = oo[dt][r] * invL;
}

// ---------------------------------------------------------------------------
extern "C" void kernel_launch(void* const* d_in, const int* in_sizes, int n_in,
                              void* d_out, int out_size, void* d_ws, size_t ws_size,
                              hipStream_t stream){
  const float* fmap = (const float*)d_in[0];
  const float* wqkv = (const float*)d_in[1];
  const float* relw = (const float*)d_in[2];
  const float* relh = (const float*)d_in[3];
  float* out = (float*)d_out;
  char* ws = (char*)d_ws;
  // workspace layout (bytes), total ~73.5 MB
  unsigned short* fmapT = (unsigned short*)(ws);                    //  8 MB
  unsigned short* Wb    = (unsigned short*)(ws + 8388608);          //  1.5 MB
  unsigned short* relwb = (unsigned short*)(ws + 9961472);          //  8 KB
  unsigned short* relhb = (unsigned short*)(ws + 9969536);          //  8 KB
  unsigned short* Qs    = (unsigned short*)(ws + 9977600);          //  8 MB (scaled q, bf16)
  unsigned short* Kb    = (unsigned short*)(ws + 18366208);         //  8 MB
  unsigned short* VT    = (unsigned short*)(ws + 26754816);         //  8 MB (V transposed [dd][i])
  float*          RWE   = (float*)(ws + 35143424);                  //  8 MB
  float*          RHE   = (float*)(ws + 43532032);                  //  8 MB

  kT<<<dim3(16,4,8), 256, 0, stream>>>(fmap, fmapT);
  kW<<<388, 256, 0, stream>>>(wqkv, relw, relh, Wb, relwb, relhb);
  kG<<<768, 256, 0, stream>>>(fmapT, Wb, Qs, Kb, VT);
  kR<<<dim3(64,8,2), 256, 0, stream>>>(Qs, relwb, relhb, RWE, RHE);
  kA<<<dim3(16,64), 256, 0, stream>>>(Qs, Kb, VT, RWE, RHE, out);
}